// Round 1
// baseline (296.007 us; speedup 1.0000x reference)
//
#include <hip/hip_runtime.h>

typedef _Float16 h16;
typedef _Float16 h16x8 __attribute__((ext_vector_type(8)));
typedef _Float16 h16x4 __attribute__((ext_vector_type(4)));
typedef float f32x4 __attribute__((ext_vector_type(4)));

#define SEQ 2048
#define RSTRIDE 8192   // b*h*d = 4*16*128
#define QTILE 128
#define KBLK 64
#define KPAD 136       // K LDS row stride (halves): 64*2+8 -> 2-way-free b128 r/w
#define VPAD 72        // Vt LDS row stride (halves)

__global__ __launch_bounds__(256, 2)
void fa_fwd_kernel(const float* __restrict__ Qg, const float* __restrict__ Kg,
                   const float* __restrict__ Vg, float* __restrict__ Out)
{
    __shared__ __attribute__((aligned(16))) h16 Kl[KBLK * KPAD];   // [key][d]
    __shared__ __attribute__((aligned(16))) h16 Vt[128 * VPAD];    // [d][key^swz]

    const int qt   = (int)gridDim.x - 1 - (int)blockIdx.x;  // heavy tiles first
    const int bh   = blockIdx.y;
    const int tid  = threadIdx.x;
    const int wave = tid >> 6;
    const int lane = tid & 63;
    const int lg   = lane >> 4;   // lane group 0..3
    const int lc   = lane & 15;   // row/col within 16
    const int q0   = qt * QTILE;
    const size_t bhoff = (size_t)bh * 128;
    const float NEGINF = -__builtin_inff();
    const float SL = 0.08838834764831845f * 1.4426950408889634f;  // (1/sqrt(128))*log2(e)

    // ---- Q fragments in registers: qf[strip][dk][j] = Q[qrow][32*dk + 8*lg + j]
    h16x8 qf[2][4];
#pragma unroll
    for (int s2 = 0; s2 < 2; ++s2) {
        const int qrow = q0 + wave * 32 + s2 * 16 + lc;
        const float* qp = Qg + (size_t)qrow * RSTRIDE + bhoff + lg * 8;
#pragma unroll
        for (int dk = 0; dk < 4; ++dk) {
            f32x4 a = *(const f32x4*)(qp + dk * 32);
            f32x4 b = *(const f32x4*)(qp + dk * 32 + 4);
            h16x8 f;
            f[0] = (h16)a[0]; f[1] = (h16)a[1]; f[2] = (h16)a[2]; f[3] = (h16)a[3];
            f[4] = (h16)b[0]; f[5] = (h16)b[1]; f[6] = (h16)b[2]; f[7] = (h16)b[3];
            qf[s2][dk] = f;
        }
    }

    // O accumulators: o[strip][dt] rows q=4*lg+reg, col lc+16*dt
    f32x4 o[2][8];
#pragma unroll
    for (int s2 = 0; s2 < 2; ++s2)
#pragma unroll
        for (int dt = 0; dt < 8; ++dt) o[s2][dt] = f32x4{0.f, 0.f, 0.f, 0.f};
    float mreg[2] = {NEGINF, NEGINF};
    float lsum[2] = {0.f, 0.f};

    const int nkv = 2 * (qt + 1);
    for (int t = 0; t < nkv; ++t) {
        const int kv0 = t * KBLK;
        __syncthreads();   // previous tile's compute done before overwrite

        // ---- stage K: [64][128] f32 -> Kl[key][d] halves, b128 writes
#pragma unroll
        for (int it = 0; it < 4; ++it) {
            const int idx = tid + it * 256;
            const int key = idx >> 4;
            const int d0  = (idx & 15) * 8;
            const float* gp = Kg + (size_t)(kv0 + key) * RSTRIDE + bhoff + d0;
            f32x4 a = *(const f32x4*)gp;
            f32x4 b = *(const f32x4*)(gp + 4);
            h16x8 f;
            f[0] = (h16)a[0]; f[1] = (h16)a[1]; f[2] = (h16)a[2]; f[3] = (h16)a[3];
            f[4] = (h16)b[0]; f[5] = (h16)b[1]; f[6] = (h16)b[2]; f[7] = (h16)b[3];
            *(h16x8*)&Kl[key * KPAD + d0] = f;
        }
        // ---- stage V transposed+swizzled: Vt[d][key ^ ((d>>2 & 15)<<2)]
        // thread remap swaps key bits0<->1 so the two half-waves hit disjoint bank parity
#pragma unroll
        for (int it = 0; it < 8; ++it) {
            const int idx  = tid + it * 256;
            const int key  = idx >> 5;
            const int vkey = (key & ~3) | ((key & 1) << 1) | ((key >> 1) & 1);
            const int d0   = (idx & 31) * 4;
            const float* gp = Vg + (size_t)(kv0 + vkey) * RSTRIDE + bhoff + d0;
            f32x4 a = *(const f32x4*)gp;
            const int col = vkey ^ (((d0 >> 2) & 15) << 2);
            Vt[(d0 + 0) * VPAD + col] = (h16)a[0];
            Vt[(d0 + 1) * VPAD + col] = (h16)a[1];
            Vt[(d0 + 2) * VPAD + col] = (h16)a[2];
            Vt[(d0 + 3) * VPAD + col] = (h16)a[3];
        }
        __syncthreads();

        // ---- compute, 2 strips of 16 q-rows per wave
#pragma unroll
        for (int s2 = 0; s2 < 2; ++s2) {
            const int qsbase = q0 + wave * 32 + s2 * 16;
            if (kv0 > qsbase + 15) continue;           // wave-uniform skip, no barriers inside
            const int qrow = qsbase + lc;              // this lane's softmax row

            // S^T = K . Q^T : sacc[kt] holds keys kv0+16*kt+4*lg+reg, q col = lc
            f32x4 sacc[4];
#pragma unroll
            for (int kt = 0; kt < 4; ++kt) sacc[kt] = f32x4{0.f, 0.f, 0.f, 0.f};
#pragma unroll
            for (int kt = 0; kt < 4; ++kt) {
#pragma unroll
                for (int dk = 0; dk < 4; ++dk) {
                    h16x8 a = *(const h16x8*)&Kl[(lc + 16 * kt) * KPAD + dk * 32 + lg * 8];
                    sacc[kt] = __builtin_amdgcn_mfma_f32_16x16x32_f16(a, qf[s2][dk], sacc[kt], 0, 0, 0);
                }
            }

            // online softmax (t-domain: s * scale * log2e)
            float pv[4][4];
            float vmax = NEGINF;
#pragma unroll
            for (int kt = 0; kt < 4; ++kt) {
#pragma unroll
                for (int r = 0; r < 4; ++r) {
                    float sv = sacc[kt][r] * SL;
                    const int key = kv0 + 16 * kt + 4 * lg + r;
                    sv = (key <= qrow) ? sv : NEGINF;
                    pv[kt][r] = sv;
                    vmax = fmaxf(vmax, sv);
                }
            }
            vmax = fmaxf(vmax, __shfl_xor(vmax, 16, 64));
            vmax = fmaxf(vmax, __shfl_xor(vmax, 32, 64));
            const float mnew  = fmaxf(mreg[s2], vmax);
            const float alpha = __builtin_exp2f(mreg[s2] - mnew);
            mreg[s2] = mnew;
            float psum = 0.f;
#pragma unroll
            for (int kt = 0; kt < 4; ++kt)
#pragma unroll
                for (int r = 0; r < 4; ++r) {
                    const float e = __builtin_exp2f(pv[kt][r] - mnew);
                    pv[kt][r] = e;
                    psum += e;
                }
            psum += __shfl_xor(psum, 16, 64);
            psum += __shfl_xor(psum, 32, 64);
            lsum[s2] = lsum[s2] * alpha + psum;

            // rescale O (rows 4*lg+r; alpha owner lane = 4*lg+r)
#pragma unroll
            for (int r = 0; r < 4; ++r) {
                const float ar = __shfl(alpha, 4 * lg + r, 64);
#pragma unroll
                for (int dt = 0; dt < 8; ++dt) o[s2][dt][r] *= ar;
            }

            // P fragments: slot (g,j) -> key 32u + 4g + (j&3) + 16*(j>>2) (all in-lane!)
            h16x8 pa[2];
#pragma unroll
            for (int u = 0; u < 2; ++u) {
                h16x8 f;
                f[0] = (h16)pv[2 * u][0];     f[1] = (h16)pv[2 * u][1];
                f[2] = (h16)pv[2 * u][2];     f[3] = (h16)pv[2 * u][3];
                f[4] = (h16)pv[2 * u + 1][0]; f[5] = (h16)pv[2 * u + 1][1];
                f[6] = (h16)pv[2 * u + 1][2]; f[7] = (h16)pv[2 * u + 1][3];
                pa[u] = f;
            }

            // PV: O[q][dcol] += P . V   (V B-frags from transposed/swizzled Vt, 2x b64 each)
#pragma unroll
            for (int dt = 0; dt < 8; ++dt) {
                const int dcol = lc + 16 * dt;
                const int swz  = ((dcol >> 2) & 15) << 2;
                const h16* vrow = &Vt[dcol * VPAD];
#pragma unroll
                for (int u = 0; u < 2; ++u) {
                    union { h16x8 v8; h16x4 v4[2]; } bv;
                    bv.v4[0] = *(const h16x4*)&vrow[(32 * u + 4 * lg) ^ swz];
                    bv.v4[1] = *(const h16x4*)&vrow[(32 * u + 16 + 4 * lg) ^ swz];
                    o[s2][dt] = __builtin_amdgcn_mfma_f32_16x16x32_f16(pa[u], bv.v8, o[s2][dt], 0, 0, 0);
                }
            }
        } // strips
    } // kv tiles

    // ---- epilogue: normalize by lsum and store f32
#pragma unroll
    for (int s2 = 0; s2 < 2; ++s2) {
#pragma unroll
        for (int r = 0; r < 4; ++r) {
            const float lr  = __shfl(lsum[s2], 4 * lg + r, 64);
            const float inv = 1.0f / lr;
            const int qrow  = q0 + wave * 32 + s2 * 16 + 4 * lg + r;
            float* op = Out + (size_t)qrow * RSTRIDE + bhoff + lc;
#pragma unroll
            for (int dt = 0; dt < 8; ++dt) op[dt * 16] = o[s2][dt][r] * inv;
        }
    }
}

extern "C" void kernel_launch(void* const* d_in, const int* in_sizes, int n_in,
                              void* d_out, int out_size, void* d_ws, size_t ws_size,
                              hipStream_t stream) {
    (void)in_sizes; (void)n_in; (void)out_size; (void)d_ws; (void)ws_size;
    const float* Q = (const float*)d_in[0];
    const float* K = (const float*)d_in[1];
    const float* V = (const float*)d_in[2];
    float* O = (float*)d_out;
    dim3 grid(SEQ / QTILE, 64);
    fa_fwd_kernel<<<grid, 256, 0, stream>>>(Q, K, V, O);
}

// Round 2
// 271.646 us; speedup vs baseline: 1.0897x; 1.0897x over previous
//
#include <hip/hip_runtime.h>

typedef _Float16 h16;
typedef _Float16 h16x8 __attribute__((ext_vector_type(8)));
typedef _Float16 h16x4 __attribute__((ext_vector_type(4)));
typedef float f32x4 __attribute__((ext_vector_type(4)));

#define SEQ 2048
#define RSTRIDE 8192   // b*h*d = 4*16*128
#define QTILE 128
#define NQT (SEQ / QTILE)   // 16
#define KBLK 64
#define KPAD 136       // K LDS row stride (halves)
#define VPAD 72        // Vt LDS row stride (halves)

__global__ __launch_bounds__(256, 2)
void fa_fwd_kernel(const float* __restrict__ Qg, const float* __restrict__ Kg,
                   const float* __restrict__ Vg, float* __restrict__ Out)
{
    __shared__ __attribute__((aligned(16))) h16 Kl[KBLK * KPAD];   // [key][d]
    __shared__ __attribute__((aligned(16))) h16 Vt[128 * VPAD];    // [d][key^swz]

    const int bx   = blockIdx.x;     // 0..7, pairs (bx, 15-bx)
    const int bh   = blockIdx.y;
    const int tid  = threadIdx.x;
    const int wave = tid >> 6;
    const int lane = tid & 63;
    const int lg   = lane >> 4;
    const int lc   = lane & 15;
    const size_t bhoff = (size_t)bh * 128;
    const float NEGINF = -__builtin_inff();
    const float SL = 0.08838834764831845f * 1.4426950408889634f;  // (1/sqrt(128))*log2(e)

    // ---- constant per-thread staging geometry
    const int krow = tid >> 4;            // + 16*it
    const int kd0  = (tid & 15) * 8;
    const float* kbase = Kg + (size_t)krow * RSTRIDE + bhoff + kd0;
    h16* kwbase = &Kl[krow * KPAD + kd0];

    const int vrow0 = tid >> 5;           // + 8*it
    const int vkeyr = (vrow0 & ~3) | ((vrow0 & 1) << 1) | ((vrow0 >> 1) & 1);
    const int vd0   = (tid & 31) * 4;
    const int vswz  = ((vd0 >> 2) & 15) << 2;
    const float* vbase = Vg + (size_t)vkeyr * RSTRIDE + bhoff + vd0;

    f32x4 kra[4], krb[4], vra[8];   // prefetch registers (T14)

    for (int half = 0; half < 2; ++half) {
        const int qt = half ? (NQT - 1 - bx) : bx;
        const int q0 = qt * QTILE;

        // ---- Q fragments: qf[strip][dk][j] = Q[qrow][32*dk + 8*lg + j]
        h16x8 qf[2][4];
#pragma unroll
        for (int s2 = 0; s2 < 2; ++s2) {
            const int qrow = q0 + wave * 32 + s2 * 16 + lc;
            const float* qp = Qg + (size_t)qrow * RSTRIDE + bhoff + lg * 8;
#pragma unroll
            for (int dk = 0; dk < 4; ++dk) {
                f32x4 a = *(const f32x4*)(qp + dk * 32);
                f32x4 b = *(const f32x4*)(qp + dk * 32 + 4);
                h16x8 f;
                f[0] = (h16)a[0]; f[1] = (h16)a[1]; f[2] = (h16)a[2]; f[3] = (h16)a[3];
                f[4] = (h16)b[0]; f[5] = (h16)b[1]; f[6] = (h16)b[2]; f[7] = (h16)b[3];
                qf[s2][dk] = f;
            }
        }

        f32x4 o[2][8];
#pragma unroll
        for (int s2 = 0; s2 < 2; ++s2)
#pragma unroll
            for (int dt = 0; dt < 8; ++dt) o[s2][dt] = f32x4{0.f, 0.f, 0.f, 0.f};
        float mreg[2] = {NEGINF, NEGINF};
        float lsum[2] = {0.f, 0.f};

        const int nkv = 2 * (qt + 1);

        // ---- prefetch tile 0 into registers
#pragma unroll
        for (int it = 0; it < 4; ++it) {
            const float* gp = kbase + (size_t)(16 * it) * RSTRIDE;
            kra[it] = *(const f32x4*)gp;
            krb[it] = *(const f32x4*)(gp + 4);
        }
#pragma unroll
        for (int it = 0; it < 8; ++it)
            vra[it] = *(const f32x4*)(vbase + (size_t)(8 * it) * RSTRIDE);

        for (int t = 0; t < nkv; ++t) {
            const int kv0 = t * KBLK;
            __syncthreads();   // previous tile's compute done before overwrite

            // ---- write staged K regs -> LDS (b128)
#pragma unroll
            for (int it = 0; it < 4; ++it) {
                f32x4 a = kra[it], b = krb[it];
                h16x8 f;
                f[0] = (h16)a[0]; f[1] = (h16)a[1]; f[2] = (h16)a[2]; f[3] = (h16)a[3];
                f[4] = (h16)b[0]; f[5] = (h16)b[1]; f[6] = (h16)b[2]; f[7] = (h16)b[3];
                *(h16x8*)(kwbase + it * 16 * KPAD) = f;
            }
            // ---- write staged V regs -> LDS transposed+swizzled
#pragma unroll
            for (int it = 0; it < 8; ++it) {
                f32x4 a = vra[it];
                const int col = (vkeyr + 8 * it) ^ vswz;
                Vt[(vd0 + 0) * VPAD + col] = (h16)a[0];
                Vt[(vd0 + 1) * VPAD + col] = (h16)a[1];
                Vt[(vd0 + 2) * VPAD + col] = (h16)a[2];
                Vt[(vd0 + 3) * VPAD + col] = (h16)a[3];
            }
            __syncthreads();

            // ---- issue next tile's global loads (hide under compute below)
            if (t + 1 < nkv) {
                const size_t toff = (size_t)(kv0 + KBLK) * RSTRIDE;
#pragma unroll
                for (int it = 0; it < 4; ++it) {
                    const float* gp = kbase + toff + (size_t)(16 * it) * RSTRIDE;
                    kra[it] = *(const f32x4*)gp;
                    krb[it] = *(const f32x4*)(gp + 4);
                }
#pragma unroll
                for (int it = 0; it < 8; ++it)
                    vra[it] = *(const f32x4*)(vbase + toff + (size_t)(8 * it) * RSTRIDE);
            }

            // ---- compute, 2 strips of 16 q-rows per wave
#pragma unroll
            for (int s2 = 0; s2 < 2; ++s2) {
                const int qsbase = q0 + wave * 32 + s2 * 16;
                if (kv0 > qsbase + 15) continue;       // wave-uniform, no barrier inside
                const int qrow = qsbase + lc;

                // S^T = K . Q^T
                f32x4 sacc[4];
#pragma unroll
                for (int kt = 0; kt < 4; ++kt) sacc[kt] = f32x4{0.f, 0.f, 0.f, 0.f};
#pragma unroll
                for (int kt = 0; kt < 4; ++kt) {
#pragma unroll
                    for (int dk = 0; dk < 4; ++dk) {
                        h16x8 a = *(const h16x8*)&Kl[(lc + 16 * kt) * KPAD + dk * 32 + lg * 8];
                        sacc[kt] = __builtin_amdgcn_mfma_f32_16x16x32_f16(a, qf[s2][dk], sacc[kt], 0, 0, 0);
                    }
                }

                // online softmax
                float pv[4][4];
                float vmax = NEGINF;
#pragma unroll
                for (int kt = 0; kt < 4; ++kt) {
#pragma unroll
                    for (int r = 0; r < 4; ++r) {
                        float sv = sacc[kt][r] * SL;
                        const int key = kv0 + 16 * kt + 4 * lg + r;
                        sv = (key <= qrow) ? sv : NEGINF;
                        pv[kt][r] = sv;
                        vmax = fmaxf(vmax, sv);
                    }
                }
                vmax = fmaxf(vmax, __shfl_xor(vmax, 16, 64));
                vmax = fmaxf(vmax, __shfl_xor(vmax, 32, 64));
                const float mnew  = fmaxf(mreg[s2], vmax);
                const float alpha = __builtin_exp2f(mreg[s2] - mnew);
                mreg[s2] = mnew;
                float psum = 0.f;
#pragma unroll
                for (int kt = 0; kt < 4; ++kt)
#pragma unroll
                    for (int r = 0; r < 4; ++r) {
                        const float e = __builtin_exp2f(pv[kt][r] - mnew);
                        pv[kt][r] = e;
                        psum += e;
                    }
                psum += __shfl_xor(psum, 16, 64);
                psum += __shfl_xor(psum, 32, 64);
                lsum[s2] = lsum[s2] * alpha + psum;

                // rescale O (alpha owner lane = 4*lg+r)
#pragma unroll
                for (int r = 0; r < 4; ++r) {
                    const float ar = __shfl(alpha, 4 * lg + r, 64);
#pragma unroll
                    for (int dt = 0; dt < 8; ++dt) o[s2][dt][r] *= ar;
                }

                // P fragments (in-lane via k-slot bijection)
                h16x8 pa[2];
#pragma unroll
                for (int u = 0; u < 2; ++u) {
                    h16x8 f;
                    f[0] = (h16)pv[2 * u][0];     f[1] = (h16)pv[2 * u][1];
                    f[2] = (h16)pv[2 * u][2];     f[3] = (h16)pv[2 * u][3];
                    f[4] = (h16)pv[2 * u + 1][0]; f[5] = (h16)pv[2 * u + 1][1];
                    f[6] = (h16)pv[2 * u + 1][2]; f[7] = (h16)pv[2 * u + 1][3];
                    pa[u] = f;
                }

                // PV
#pragma unroll
                for (int dt = 0; dt < 8; ++dt) {
                    const int dcol = lc + 16 * dt;
                    const int swz  = ((dcol >> 2) & 15) << 2;
                    const h16* vrow = &Vt[dcol * VPAD];
#pragma unroll
                    for (int u = 0; u < 2; ++u) {
                        union { h16x8 v8; h16x4 v4[2]; } bv;
                        bv.v4[0] = *(const h16x4*)&vrow[(32 * u + 4 * lg) ^ swz];
                        bv.v4[1] = *(const h16x4*)&vrow[(32 * u + 16 + 4 * lg) ^ swz];
                        o[s2][dt] = __builtin_amdgcn_mfma_f32_16x16x32_f16(pa[u], bv.v8, o[s2][dt], 0, 0, 0);
                    }
                }
            } // strips
        } // kv tiles

        // ---- epilogue
#pragma unroll
        for (int s2 = 0; s2 < 2; ++s2) {
#pragma unroll
            for (int r = 0; r < 4; ++r) {
                const float lr  = __shfl(lsum[s2], 4 * lg + r, 64);
                const float inv = 1.0f / lr;
                const int qrow  = q0 + wave * 32 + s2 * 16 + 4 * lg + r;
                float* op = Out + (size_t)qrow * RSTRIDE + bhoff + lc;
#pragma unroll
                for (int dt = 0; dt < 8; ++dt) op[dt * 16] = o[s2][dt][r] * inv;
            }
        }
    } // half
}

extern "C" void kernel_launch(void* const* d_in, const int* in_sizes, int n_in,
                              void* d_out, int out_size, void* d_ws, size_t ws_size,
                              hipStream_t stream) {
    (void)in_sizes; (void)n_in; (void)out_size; (void)d_ws; (void)ws_size;
    const float* Q = (const float*)d_in[0];
    const float* K = (const float*)d_in[1];
    const float* V = (const float*)d_in[2];
    float* O = (float*)d_out;
    dim3 grid(NQT / 2, 64);
    fa_fwd_kernel<<<grid, 256, 0, stream>>>(Q, K, V, O);
}